// Round 8
// baseline (335.208 us; speedup 1.0000x reference)
//
#include <hip/hip_runtime.h>
#include <cstdint>
#include <cstddef>

typedef unsigned short u16;
typedef __attribute__((ext_vector_type(8))) short short8;
typedef __attribute__((ext_vector_type(4))) float float4v;

struct alignas(8) u16x4 { u16 x, y, z, w; };

__device__ __forceinline__ float bf2f(u16 u) {
  union { uint32_t i; float f; } x;
  x.i = ((uint32_t)u) << 16;
  return x.f;
}
__device__ __forceinline__ u16 f2bf(float f) {
  union { float f; uint32_t i; } x;
  x.f = f;
  uint32_t r = x.i + 0x7fffu + ((x.i >> 16) & 1u);  // RNE
  return (u16)(r >> 16);
}
__device__ __forceinline__ int4 pack8(const float4& a, const float4& b) {
  int4 r;
  r.x = (uint32_t)f2bf(a.x) | ((uint32_t)f2bf(a.y) << 16);
  r.y = (uint32_t)f2bf(a.z) | ((uint32_t)f2bf(a.w) << 16);
  r.z = (uint32_t)f2bf(b.x) | ((uint32_t)f2bf(b.y) << 16);
  r.w = (uint32_t)f2bf(b.z) | ((uint32_t)f2bf(b.w) << 16);
  return r;
}

// async global->LDS, 16 B per lane; LDS dest = wave-uniform base + lane*16.
__device__ __forceinline__ void gload_lds16(const void* g, void* l) {
  __builtin_amdgcn_global_load_lds(
      (const __attribute__((address_space(1))) void*)g,
      (__attribute__((address_space(3))) void*)l, 16, 0, 0);
}

// counted-vmcnt wait + raw barrier + compile-time fence (rule #18).
#define WAITV_BAR(N)                                              \
  do {                                                            \
    asm volatile("s_waitcnt vmcnt(%0)" ::"n"(N) : "memory");      \
    __builtin_amdgcn_s_barrier();                                 \
    __builtin_amdgcn_sched_barrier(0);                            \
  } while (0)

#define BAR_ONLY()                                                \
  do {                                                            \
    __builtin_amdgcn_sched_barrier(0);                            \
    __builtin_amdgcn_s_barrier();                                 \
    __builtin_amdgcn_sched_barrier(0);                            \
  } while (0)

#define LGKM0_FENCE()                                             \
  do {                                                            \
    asm volatile("s_waitcnt lgkmcnt(0)" ::: "memory");            \
    __builtin_amdgcn_sched_barrier(0);                            \
  } while (0)

// ---------------------------------------------------------------------------
// XCD-aware block swizzle (T1). All grids used here have nwg % 8 == 0.
// ---------------------------------------------------------------------------
__device__ __forceinline__ int2 xcd_swizzle_xmajor() {
  const int gx = gridDim.x, gy = gridDim.y;
  const int nwg = gx * gy;
  const int lin = blockIdx.x + blockIdx.y * gx;   // HW dispatch order
  const int nl = (lin & 7) * (nwg >> 3) + (lin >> 3);
  const int bx = nl / gy;
  const int by = nl - bx * gy;
  return make_int2(bx, by);
}

// ---------------------------------------------------------------------------
// Weight prep: fp32 -> bf16 for the 5 weight matrices. UNCHANGED.
// ---------------------------------------------------------------------------
struct PrepArgs {
  const float* src[5];
  u16* dst[5];
  int pre[6];
};

__global__ __launch_bounds__(256) void prep_kernel(PrepArgs a)
{
  const int g = blockIdx.x * 256 + threadIdx.x;
  if (g >= a.pre[5]) return;
  int t = 0;
#pragma unroll
  for (int i = 0; i < 5; i++) if (g >= a.pre[i + 1]) t = i + 1;
  const int idx = (g - a.pre[t]) * 8;
  const float* s = a.src[t] + idx;
  float4 v0 = *(const float4*)(s);
  float4 v1 = *(const float4*)(s + 4);
  *(int4*)(a.dst[t] + idx) = pack8(v0, v1);
}

// ---------------------------------------------------------------------------
// GEMM_BT — r18: r17 phase template ported to single-B. 512 threads, BM=128,
// BN=128, BK=64, 3-deep buffers (96 KB, 1 block/CU, 8 waves). Two phases per
// K-tile split by 32-K slice (8-MFMA clusters); vmcnt counted ONCE per tile:
//  phA: {6 ds_read ks=0 | issue A(i+2) | BAR | lgkm0 | prio1 8 MFMA prio0 | BAR}
//  phB: {6 ds_read ks=1 | issue B(i+2) | BAR | lgkm0 | prio1 8 MFMA prio0 |
//        vmcnt(4)+BAR}
// Grid quantization: qkv 768 = 3 exact rounds; wo/w2 256 = 1 exact round
// (BN 64->128 also halves their A re-fetch). Stage/read swizzle = validated
// BK=64 math (slot^(row&7)).
// ---------------------------------------------------------------------------
template <int RMODE, bool OUTF32>
__global__ __launch_bounds__(512) void gemm_bt_kernel(
    const u16* __restrict__ A, const u16* __restrict__ B,
    void* __restrict__ Cv, const void* __restrict__ Rv,
    int M, int N, int K)
{
  __shared__ u16 As[3][128 * 64];    // 16 KB per buf
  __shared__ u16 Bs[3][128 * 64];
  const int t = threadIdx.x;
  const int lane = t & 63;
  const int wave = t >> 6;           // 0..7
  const int l15 = lane & 15;
  const int quad = lane >> 4;
  const int wm = (wave >> 2) * 64;   // 2 M-waves
  const int wn = (wave & 3) * 32;    // 4 N-waves
  const int2 bb = xcd_swizzle_xmajor();
  const int m0 = bb.y * 128;
  const int n0 = bb.x * 128;

  float4v acc[4][2] = {};

  const int sub = lane >> 3;         // row within the wave's 8-row group
  const int slot = lane & 7;         // 16B slot within the 128B row

  auto stageA = [&](int bi, int kt) {
#pragma unroll
    for (int j = 0; j < 2; j++) {
      const int r = j * 64 + wave * 8 + sub;
      gload_lds16(A + (size_t)(m0 + r) * K + kt + ((slot ^ (r & 7)) * 8),
                  &As[bi][j * 4096 + wave * 512]);
    }
  };
  auto stageB = [&](int bi, int kt) {
#pragma unroll
    for (int j = 0; j < 2; j++) {
      const int r = j * 64 + wave * 8 + sub;
      gload_lds16(B + (size_t)(n0 + r) * K + kt + ((slot ^ (r & 7)) * 8),
                  &Bs[bi][j * 4096 + wave * 512]);
    }
  };

  const int nkt = K >> 6;            // K-tiles; >= 16 at all call sites
  // prologue: fully stage tiles 0 and 1 (8 loads/wave)
  stageA(0, 0);  stageB(0, 0);
  stageA(1, 64); stageB(1, 64);
  WAITV_BAR(4);                      // tile0 landed; tile1 in flight

  int cur = 0;
  for (int i = 0; i < nkt; ++i) {
    const int stg = (cur >= 1) ? cur - 1 : 2;   // (cur+2)%3
    const int kt2 = (i + 2) << 6;
    // ---------------- phase A (ks = 0) ----------------
    short8 af0[4], bf0[2];
#pragma unroll
    for (int ii = 0; ii < 4; ii++) {
      const int R = wm + ii * 16 + l15;
      af0[ii] = *(const short8*)(&As[cur][R * 64 + ((quad ^ (R & 7)) * 8)]);
    }
#pragma unroll
    for (int j = 0; j < 2; j++) {
      const int R = wn + j * 16 + l15;
      bf0[j] = *(const short8*)(&Bs[cur][R * 64 + ((quad ^ (R & 7)) * 8)]);
    }
    if (i + 2 < nkt) stageA(stg, kt2);
    __builtin_amdgcn_s_barrier();
    LGKM0_FENCE();
    __builtin_amdgcn_s_setprio(1);
#pragma unroll
    for (int ii = 0; ii < 4; ii++)
#pragma unroll
      for (int j = 0; j < 2; j++)
        acc[ii][j] = __builtin_amdgcn_mfma_f32_16x16x32_bf16(af0[ii], bf0[j], acc[ii][j], 0, 0, 0);
    __builtin_amdgcn_s_setprio(0);
    BAR_ONLY();
    // ---------------- phase B (ks = 1) ----------------
    short8 af1[4], bf1[2];
#pragma unroll
    for (int ii = 0; ii < 4; ii++) {
      const int R = wm + ii * 16 + l15;
      af1[ii] = *(const short8*)(&As[cur][R * 64 + (((4 + quad) ^ (R & 7)) * 8)]);
    }
#pragma unroll
    for (int j = 0; j < 2; j++) {
      const int R = wn + j * 16 + l15;
      bf1[j] = *(const short8*)(&Bs[cur][R * 64 + (((4 + quad) ^ (R & 7)) * 8)]);
    }
    if (i + 2 < nkt) stageB(stg, kt2);
    __builtin_amdgcn_s_barrier();
    LGKM0_FENCE();
    __builtin_amdgcn_s_setprio(1);
#pragma unroll
    for (int ii = 0; ii < 4; ii++)
#pragma unroll
      for (int j = 0; j < 2; j++)
        acc[ii][j] = __builtin_amdgcn_mfma_f32_16x16x32_bf16(af1[ii], bf1[j], acc[ii][j], 0, 0, 0);
    __builtin_amdgcn_s_setprio(0);
    // end-of-tile counted wait: tile i+1 landed; tile i+2 stays in flight
    if (i + 2 < nkt)      WAITV_BAR(4);
    else if (i + 1 < nkt) WAITV_BAR(0);
    cur = (cur == 2) ? 0 : cur + 1;
  }

#pragma unroll
  for (int i = 0; i < 4; i++) {
#pragma unroll
    for (int r = 0; r < 4; r++) {
      const int row = m0 + wm + i * 16 + quad * 4 + r;
      const size_t base = (size_t)row * N;
#pragma unroll
      for (int j = 0; j < 2; j++) {
        const int col = n0 + wn + j * 16 + l15;
        float v = acc[i][j][r];
        if (RMODE == 1) v += ((const float*)Rv)[base + col];
        if (RMODE == 2) v += bf2f(((const u16*)Rv)[base + col]);
        if (OUTF32) ((float*)Cv)[base + col] = v;
        else        ((u16*)Cv)[base + col] = f2bf(v);
      }
    }
  }
}

// ---------------------------------------------------------------------------
// Fused FFN up-projection — UNCHANGED from r17 (65.0 us measured).
// ---------------------------------------------------------------------------
__global__ __launch_bounds__(512) void gemm_w13_kernel(
    const u16* __restrict__ A, const u16* __restrict__ B1,
    const u16* __restrict__ B2, u16* __restrict__ C,
    int M, int N, int K)
{
  __shared__ u16 As[3][128 * 64];    // 16 KB per buf
  __shared__ u16 B1s[3][128 * 64];
  __shared__ u16 B2s[3][128 * 64];
  const int t = threadIdx.x;
  const int lane = t & 63;
  const int wave = t >> 6;           // 0..7
  const int l15 = lane & 15;
  const int quad = lane >> 4;
  const int wm = (wave >> 2) * 64;   // 2 M-waves
  const int wn = (wave & 3) * 32;    // 4 N-waves
  const int2 bb = xcd_swizzle_xmajor();
  const int m0 = bb.y * 128;
  const int n0 = bb.x * 128;

  float4v accA[4][2] = {};
  float4v accB[4][2] = {};

  const int sub = lane >> 3;         // row within the wave's 8-row group
  const int slot = lane & 7;         // 16B slot within the 128B row

  auto stageA = [&](int bi, int kt) {
#pragma unroll
    for (int j = 0; j < 2; j++) {
      const int r = j * 64 + wave * 8 + sub;
      gload_lds16(A + (size_t)(m0 + r) * K + kt + ((slot ^ (r & 7)) * 8),
                  &As[bi][j * 4096 + wave * 512]);
    }
  };
  auto stageB1 = [&](int bi, int kt) {
#pragma unroll
    for (int j = 0; j < 2; j++) {
      const int r = j * 64 + wave * 8 + sub;
      gload_lds16(B1 + (size_t)(n0 + r) * K + kt + ((slot ^ (r & 7)) * 8),
                  &B1s[bi][j * 4096 + wave * 512]);
    }
  };
  auto stageB2 = [&](int bi, int kt) {
#pragma unroll
    for (int j = 0; j < 2; j++) {
      const int r = j * 64 + wave * 8 + sub;
      gload_lds16(B2 + (size_t)(n0 + r) * K + kt + ((slot ^ (r & 7)) * 8),
                  &B2s[bi][j * 4096 + wave * 512]);
    }
  };

  const int nkt = K >> 6;            // 16 K-tiles
  // prologue: fully stage tiles 0 and 1 (12 loads/wave)
  stageA(0, 0);  stageB1(0, 0);  stageB2(0, 0);
  stageA(1, 64); stageB1(1, 64); stageB2(1, 64);
  WAITV_BAR(6);                      // tile0 landed; tile1 in flight

  int cur = 0;
  for (int i = 0; i < nkt; ++i) {
    const int stg = (cur >= 1) ? cur - 1 : 2;   // (cur+2)%3, tile i+2's buffer
    const int kt2 = (i + 2) << 6;
    // ---------------- phase A ----------------
    short8 af[4][2], b1f[2][2];
#pragma unroll
    for (int ii = 0; ii < 4; ii++) {
      const int R = wm + ii * 16 + l15;
#pragma unroll
      for (int ks = 0; ks < 2; ks++)
        af[ii][ks] = *(const short8*)(&As[cur][R * 64 + (((ks * 4 + quad) ^ (R & 7)) * 8)]);
    }
#pragma unroll
    for (int j = 0; j < 2; j++) {
      const int R = wn + j * 16 + l15;
#pragma unroll
      for (int ks = 0; ks < 2; ks++)
        b1f[j][ks] = *(const short8*)(&B1s[cur][R * 64 + (((ks * 4 + quad) ^ (R & 7)) * 8)]);
    }
    if (i + 2 < nkt) { stageA(stg, kt2); stageB1(stg, kt2); }
    __builtin_amdgcn_s_barrier();
    LGKM0_FENCE();
    __builtin_amdgcn_s_setprio(1);
#pragma unroll
    for (int ii = 0; ii < 4; ii++)
#pragma unroll
      for (int j = 0; j < 2; j++)
#pragma unroll
        for (int ks = 0; ks < 2; ks++)
          accA[ii][j] = __builtin_amdgcn_mfma_f32_16x16x32_bf16(af[ii][ks], b1f[j][ks], accA[ii][j], 0, 0, 0);
    __builtin_amdgcn_s_setprio(0);
    BAR_ONLY();
    // ---------------- phase B ----------------
    short8 b2f[2][2];
#pragma unroll
    for (int j = 0; j < 2; j++) {
      const int R = wn + j * 16 + l15;
#pragma unroll
      for (int ks = 0; ks < 2; ks++)
        b2f[j][ks] = *(const short8*)(&B2s[cur][R * 64 + (((ks * 4 + quad) ^ (R & 7)) * 8)]);
    }
    if (i + 2 < nkt) stageB2(stg, kt2);
    __builtin_amdgcn_s_barrier();
    LGKM0_FENCE();
    __builtin_amdgcn_s_setprio(1);
#pragma unroll
    for (int ii = 0; ii < 4; ii++)
#pragma unroll
      for (int j = 0; j < 2; j++)
#pragma unroll
        for (int ks = 0; ks < 2; ks++)
          accB[ii][j] = __builtin_amdgcn_mfma_f32_16x16x32_bf16(af[ii][ks], b2f[j][ks], accB[ii][j], 0, 0, 0);
    __builtin_amdgcn_s_setprio(0);
    // end-of-tile counted wait: tile i+1 must be landed before next iter reads
    if (i + 2 < nkt)      WAITV_BAR(6);   // tile i+2 (6 loads) stays in flight
    else if (i + 1 < nkt) WAITV_BAR(0);   // drain last staged tile
    cur = (cur == 2) ? 0 : cur + 1;
  }

#pragma unroll
  for (int i = 0; i < 4; i++) {
#pragma unroll
    for (int r = 0; r < 4; r++) {
      const int row = m0 + wm + i * 16 + quad * 4 + r;
      const size_t base = (size_t)row * N;
#pragma unroll
      for (int j = 0; j < 2; j++) {
        const int col = n0 + wn + j * 16 + l15;
        float a = accA[i][j][r];
        float b = accB[i][j][r];
        float h = a / (1.f + __expf(-a)) * b;
        C[base + col] = f2bf(h);
      }
    }
  }
}

// ---------------------------------------------------------------------------
// V transpose — UNCHANGED.
// ---------------------------------------------------------------------------
__global__ __launch_bounds__(256) void vtrans_kernel(
    const u16* __restrict__ qkv, u16* __restrict__ VtG)
{
  __shared__ u16 T[64 * 72];
  const int t = threadIdx.x;
  const int s0 = blockIdx.x * 64;
  const int bh = blockIdx.y, b = bh >> 4, h = bh & 15;
  {
    const int sl = t >> 2, dseg = (t & 3) * 16;
    const size_t src = ((size_t)b * 2048 + s0 + sl) * 3072 + 2048 + h * 64 + dseg;
    int4 v0 = *(const int4*)(qkv + src);
    int4 v1 = *(const int4*)(qkv + src + 8);
    *(int4*)(&T[sl * 72 + dseg]) = v0;
    *(int4*)(&T[sl * 72 + dseg + 8]) = v1;
  }
  __syncthreads();
  {
    const int d = t >> 2, sseg = (t & 3) * 16;
    alignas(16) u16 buf[16];
#pragma unroll
    for (int i = 0; i < 16; i++) buf[i] = T[(sseg + i) * 72 + d];
    u16* dst = VtG + ((size_t)bh * 64 + d) * 2048 + s0 + sseg;
    *(int4*)(dst) = *(const int4*)(&buf[0]);
    *(int4*)(dst + 8) = *(const int4*)(&buf[8]);
  }
}

// ---------------------------------------------------------------------------
// Causal flash attention v2 — UNCHANGED from r12.
// ---------------------------------------------------------------------------
__global__ __launch_bounds__(256) void attn_kernel(
    const u16* __restrict__ qkv, const u16* __restrict__ VtG,
    u16* __restrict__ outp)
{
  __shared__ u16 Ks[2][2][128 * 32];
  __shared__ u16 Vt[2][4][64 * 32];
  __shared__ u16 Pl[4][2048];
  const int t = threadIdx.x;
  const int lane = t & 63;
  const int wave = t >> 6;
  const int l15 = lane & 15;
  const int quad = lane >> 4;
  const int sw = quad ^ ((l15 >> 1) & 3);
  // bh-major XCD swizzle
  const int gx = gridDim.x;                       // 16
  const int nwg = gx * gridDim.y;                 // 512
  const int lin = blockIdx.x + blockIdx.y * gx;
  const int nl = (lin & 7) * (nwg >> 3) + (lin >> 3);
  const int bh = nl / gx;
  const int pair = nl - bh * gx;
  const int b = bh >> 4, h = bh & 15;
  const size_t srow = (size_t)b * 2048;
  const int rr = lane >> 2, qs = (lane & 3) ^ ((lane >> 3) & 3);
  u16* plw = Pl[wave];

  auto stageKV = [&](int bi, int ic) {
    const int c0 = ic * 128;
#pragma unroll
    for (int k = 0; k < 8; k++) {
      const int I = wave * 8 + k;
      if (I < 16) {
        const int half = I >> 3, rb = (I & 7) * 16, row = rb + rr;
        gload_lds16(qkv + (srow + c0 + row) * 3072 + 1024 + h * 64 + half * 32 + qs * 8,
                    &Ks[bi][half][rb * 32]);
      } else {
        const int g = (I - 16) >> 2, rb = ((I - 16) & 3) * 16, row = rb + rr;
        gload_lds16(VtG + ((size_t)bh * 64 + row) * 2048 + c0 + g * 32 + qs * 8,
                    &Vt[bi][g][rb * 32]);
      }
    }
  };

  for (int tsel = 0; tsel < 2; tsel++) {
    const int qt = tsel ? 31 - pair : pair;
    const int tq0 = qt * 64;
    const int q = tq0 + wave * 16 + l15;

    short8 qf[2];
    {
      const size_t qbase = (srow + q) * 3072 + h * 64;
#pragma unroll
      for (int dh = 0; dh < 2; dh++) {
        int4 raw = *(const int4*)(qkv + qbase + dh * 32 + quad * 8);
        const u16* rp = (const u16*)&raw;
        short8 f;
#pragma unroll
        for (int j = 0; j < 8; j++)
          ((u16*)&f)[j] = f2bf(bf2f(rp[j]) * 0.125f);
        qf[dh] = f;
      }
    }

    float m_i = -INFINITY, l_i = 0.f;
    float4v accO[4] = {};
    const int nc = (qt + 2) >> 1;

    stageKV(0, 0);
    for (int ic = 0; ic < nc; ic++) {
      const int cb = ic & 1;
      const int c0 = ic * 128;
      if (ic + 1 < nc) {
        stageKV(cb ^ 1, ic + 1);
        WAITV_BAR(8);              // chunk ic ready; ic+1 stays in flight
      } else {
        WAITV_BAR(0);
      }

      float4v accS[8];
#pragma unroll
      for (int ks = 0; ks < 8; ks++) {
        short8 kf0 = *(const short8*)(&Ks[cb][0][((ks * 16 + l15) * 4 + sw) * 8]);
        short8 kf1 = *(const short8*)(&Ks[cb][1][((ks * 16 + l15) * 4 + sw) * 8]);
        float4v z = {};
        z = __builtin_amdgcn_mfma_f32_16x16x32_bf16(kf0, qf[0], z, 0, 0, 0);
        accS[ks] = __builtin_amdgcn_mfma_f32_16x16x32_bf16(kf1, qf[1], z, 0, 0, 0);
      }

      if (ic == nc - 1) {
#pragma unroll
        for (int ks = 0; ks < 8; ks++)
#pragma unroll
          for (int r = 0; r < 4; r++)
            if (c0 + ks * 16 + quad * 4 + r > q) accS[ks][r] = -INFINITY;
      }

      float cmax = -INFINITY;
#pragma unroll
      for (int ks = 0; ks < 8; ks++)
#pragma unroll
        for (int r = 0; r < 4; r++) cmax = fmaxf(cmax, accS[ks][r]);
      cmax = fmaxf(cmax, __shfl_xor(cmax, 16));
      cmax = fmaxf(cmax, __shfl_xor(cmax, 32));
      const float mn = fmaxf(m_i, cmax);
      const float alpha = __expf(m_i - mn);

      float psum = 0.f;
#pragma unroll
      for (int ks = 0; ks < 8; ks++) {
        float p0 = __expf(accS[ks][0] - mn);
        float p1 = __expf(accS[ks][1] - mn);
        float p2 = __expf(accS[ks][2] - mn);
        float p3 = __expf(accS[ks][3] - mn);
        psum += (p0 + p1) + (p2 + p3);
        u16x4 pk;
        pk.x = f2bf(p0); pk.y = f2bf(p1); pk.z = f2bf(p2); pk.w = f2bf(p3);
        const int seg = ((ks & 1) * 2 + (quad >> 1)) ^ ((l15 >> 1) & 3);
        *(u16x4*)(&plw[(ks >> 1) * 512 + (l15 * 4 + seg) * 8 + (quad & 1) * 4]) = pk;
      }
      psum += __shfl_xor(psum, 16);
      psum += __shfl_xor(psum, 32);
      l_i = l_i * alpha + psum;
      m_i = mn;
#pragma unroll
      for (int ds = 0; ds < 4; ds++)
#pragma unroll
        for (int r = 0; r < 4; r++) accO[ds][r] *= alpha;

      __threadfence_block();

#pragma unroll
      for (int kh = 0; kh < 4; kh++) {
        short8 pf = *(const short8*)(&plw[kh * 512 + (l15 * 4 + sw) * 8]);
#pragma unroll
        for (int ds = 0; ds < 4; ds++) {
          short8 vf = *(const short8*)(&Vt[cb][kh][((ds * 16 + l15) * 4 + sw) * 8]);
          accO[ds] = __builtin_amdgcn_mfma_f32_16x16x32_bf16(vf, pf, accO[ds], 0, 0, 0);
        }
      }
      BAR_ONLY();                  // buffer cb safe to restage next iteration
    }

    const float invl = 1.f / l_i;
    const size_t obase = (srow + q) * 1024 + h * 64;
#pragma unroll
    for (int ds = 0; ds < 4; ds++) {
      u16x4 pk;
      pk.x = f2bf(accO[ds][0] * invl);
      pk.y = f2bf(accO[ds][1] * invl);
      pk.z = f2bf(accO[ds][2] * invl);
      pk.w = f2bf(accO[ds][3] * invl);
      *(u16x4*)(outp + obase + ds * 16 + quad * 4) = pk;
    }
  }
}

// ---------------------------------------------------------------------------
// RMSNorm — UNCHANGED.
// ---------------------------------------------------------------------------
template <bool XF32>
__global__ __launch_bounds__(256) void rmsnorm_kernel(
    const void* __restrict__ xv, const float* __restrict__ g, u16* __restrict__ o)
{
  const int row = blockIdx.x;
  const int t = threadIdx.x;
  float f0, f1, f2, f3;
  if (XF32) {
    float4 v = *(const float4*)((const float*)xv + (size_t)row * 1024 + t * 4);
    f0 = v.x; f1 = v.y; f2 = v.z; f3 = v.w;
  } else {
    int2 v = *(const int2*)((const u16*)xv + (size_t)row * 1024 + t * 4);
    const u16* p = (const u16*)&v;
    f0 = bf2f(p[0]); f1 = bf2f(p[1]); f2 = bf2f(p[2]); f3 = bf2f(p[3]);
  }
  float ss = f0 * f0 + f1 * f1 + f2 * f2 + f3 * f3;
#pragma unroll
  for (int off = 32; off > 0; off >>= 1) ss += __shfl_down(ss, off);
  __shared__ float red[4];
  if ((t & 63) == 0) red[t >> 6] = ss;
  __syncthreads();
  const float tot = red[0] + red[1] + red[2] + red[3];
  const float inv = rsqrtf(tot * (1.0f / 1024.0f) + 1e-5f);
  float4 gv = *(const float4*)(g + t * 4);
  u16x4 ov;
  ov.x = f2bf(f0 * gv.x * inv);
  ov.y = f2bf(f1 * gv.y * inv);
  ov.z = f2bf(f2 * gv.z * inv);
  ov.w = f2bf(f3 * gv.w * inv);
  *(u16x4*)(o + (size_t)row * 1024 + t * 4) = ov;
}

// ---------------------------------------------------------------------------
// Inputs (fp32): x wqkv wo g1 g2 w1 w2 w3. OUTPUT fp32.
// ws (72 MB): bf16 weights 24 + S1 8 + S2 24 + S3 8 + VtG 8.
// ---------------------------------------------------------------------------
extern "C" void kernel_launch(void* const* d_in, const int* in_sizes, int n_in,
                              void* d_out, int out_size, void* d_ws, size_t ws_size,
                              hipStream_t stream)
{
  const float* x    = (const float*)d_in[0];
  const float* wqkv = (const float*)d_in[1];
  const float* wo   = (const float*)d_in[2];
  const float* g1   = (const float*)d_in[3];
  const float* g2   = (const float*)d_in[4];
  const float* w1   = (const float*)d_in[5];
  const float* w2   = (const float*)d_in[6];
  const float* w3   = (const float*)d_in[7];
  float* out = (float*)d_out;
  char* ws = (char*)d_ws;
  (void)in_sizes; (void)n_in; (void)out_size; (void)ws_size;

  size_t off = 0;
  auto alloc = [&](size_t bytes) { void* p = ws + off; off += (bytes + 255) & ~(size_t)255; return p; };
  u16* wqkvb = (u16*)alloc((size_t)3072 * 1024 * 2);
  u16* wob   = (u16*)alloc((size_t)1024 * 1024 * 2);
  u16* w1b   = (u16*)alloc((size_t)2688 * 1024 * 2);
  u16* w2b   = (u16*)alloc((size_t)2688 * 1024 * 2);
  u16* w3b   = (u16*)alloc((size_t)2688 * 1024 * 2);
  u16* S1    = (u16*)alloc((size_t)4096 * 1024 * 2);
  u16* S2    = (u16*)alloc((size_t)4096 * 3072 * 2);
  u16* S3    = (u16*)alloc((size_t)4096 * 1024 * 2);
  u16* VtG   = (u16*)alloc((size_t)32 * 64 * 2048 * 2);

  PrepArgs pa;
  const float* srcs[5] = {wqkv, wo, w1, w2, w3};
  u16* dsts[5] = {wqkvb, wob, w1b, w2b, w3b};
  const int nelem[5] = {3072 * 1024, 1024 * 1024, 2688 * 1024, 2688 * 1024, 2688 * 1024};
  int pre = 0;
  for (int i = 0; i < 5; i++) {
    pa.src[i] = srcs[i];
    pa.dst[i] = dsts[i];
    pa.pre[i] = pre;
    pre += nelem[i] / 8;
  }
  pa.pre[5] = pre;
  prep_kernel<<<(pre + 255) / 256, 256, 0, stream>>>(pa);

  rmsnorm_kernel<true><<<4096, 256, 0, stream>>>(x, g1, S1);                        // xn
  gemm_bt_kernel<0, false><<<dim3(24, 32), 512, 0, stream>>>(S1, wqkvb, S2,
                                                  nullptr, 4096, 3072, 1024);       // qkv
  vtrans_kernel<<<dim3(32, 32), 256, 0, stream>>>(S2, VtG);                         // V^T
  attn_kernel<<<dim3(16, 32), 256, 0, stream>>>(S2, VtG, S1);                       // att
  gemm_bt_kernel<1, false><<<dim3(8, 32), 512, 0, stream>>>(S1, wob, S3, x,
                                                  4096, 1024, 1024);                // x1
  rmsnorm_kernel<false><<<4096, 256, 0, stream>>>(S3, g2, S1);                      // xn2
  gemm_w13_kernel<<<dim3(21, 32), 512, 0, stream>>>(S1, w1b, w3b, S2,
                                                  4096, 2688, 1024);                // h
  gemm_bt_kernel<2, true><<<dim3(8, 32), 512, 0, stream>>>(S2, w2b, out, S3,
                                                  4096, 1024, 2688);                // out fp32
}

// Round 9
// 323.527 us; speedup vs baseline: 1.0361x; 1.0361x over previous
//
#include <hip/hip_runtime.h>
#include <cstdint>
#include <cstddef>

typedef unsigned short u16;
typedef __attribute__((ext_vector_type(8))) short short8;
typedef __attribute__((ext_vector_type(4))) float float4v;

struct alignas(8) u16x4 { u16 x, y, z, w; };

__device__ __forceinline__ float bf2f(u16 u) {
  union { uint32_t i; float f; } x;
  x.i = ((uint32_t)u) << 16;
  return x.f;
}
__device__ __forceinline__ u16 f2bf(float f) {
  union { float f; uint32_t i; } x;
  x.f = f;
  uint32_t r = x.i + 0x7fffu + ((x.i >> 16) & 1u);  // RNE
  return (u16)(r >> 16);
}
__device__ __forceinline__ int4 pack8(const float4& a, const float4& b) {
  int4 r;
  r.x = (uint32_t)f2bf(a.x) | ((uint32_t)f2bf(a.y) << 16);
  r.y = (uint32_t)f2bf(a.z) | ((uint32_t)f2bf(a.w) << 16);
  r.z = (uint32_t)f2bf(b.x) | ((uint32_t)f2bf(b.y) << 16);
  r.w = (uint32_t)f2bf(b.z) | ((uint32_t)f2bf(b.w) << 16);
  return r;
}

// async global->LDS, 16 B per lane; LDS dest = wave-uniform base + lane*16.
__device__ __forceinline__ void gload_lds16(const void* g, void* l) {
  __builtin_amdgcn_global_load_lds(
      (const __attribute__((address_space(1))) void*)g,
      (__attribute__((address_space(3))) void*)l, 16, 0, 0);
}

// counted-vmcnt wait + raw barrier + compile-time fence (rule #18).
#define WAITV_BAR(N)                                              \
  do {                                                            \
    asm volatile("s_waitcnt vmcnt(%0)" ::"n"(N) : "memory");      \
    __builtin_amdgcn_s_barrier();                                 \
    __builtin_amdgcn_sched_barrier(0);                            \
  } while (0)

#define BAR_ONLY()                                                \
  do {                                                            \
    __builtin_amdgcn_sched_barrier(0);                            \
    __builtin_amdgcn_s_barrier();                                 \
    __builtin_amdgcn_sched_barrier(0);                            \
  } while (0)

#define LGKM0_FENCE()                                             \
  do {                                                            \
    asm volatile("s_waitcnt lgkmcnt(0)" ::: "memory");            \
    __builtin_amdgcn_sched_barrier(0);                            \
  } while (0)

// ---------------------------------------------------------------------------
// XCD-aware block swizzle (T1). All grids used here have nwg % 8 == 0.
// ---------------------------------------------------------------------------
__device__ __forceinline__ int2 xcd_swizzle_xmajor() {
  const int gx = gridDim.x, gy = gridDim.y;
  const int nwg = gx * gy;
  const int lin = blockIdx.x + blockIdx.y * gx;   // HW dispatch order
  const int nl = (lin & 7) * (nwg >> 3) + (lin >> 3);
  const int bx = nl / gy;
  const int by = nl - bx * gy;
  return make_int2(bx, by);
}

// ---------------------------------------------------------------------------
// Weight prep: fp32 -> bf16 for the 5 weight matrices. UNCHANGED.
// ---------------------------------------------------------------------------
struct PrepArgs {
  const float* src[5];
  u16* dst[5];
  int pre[6];
};

__global__ __launch_bounds__(256) void prep_kernel(PrepArgs a)
{
  const int g = blockIdx.x * 256 + threadIdx.x;
  if (g >= a.pre[5]) return;
  int t = 0;
#pragma unroll
  for (int i = 0; i < 5; i++) if (g >= a.pre[i + 1]) t = i + 1;
  const int idx = (g - a.pre[t]) * 8;
  const float* s = a.src[t] + idx;
  float4 v0 = *(const float4*)(s);
  float4 v1 = *(const float4*)(s + 4);
  *(int4*)(a.dst[t] + idx) = pack8(v0, v1);
}

// ---------------------------------------------------------------------------
// GEMM_BT — reverted to r12/r17 version (3-deep counted-vmcnt pipeline,
// 256 threads): present in every best-total build. r18's 512-thr port was
// neutral-to-negative.
// ---------------------------------------------------------------------------
template <int RMODE, bool OUTF32, int TN>
__global__ __launch_bounds__(256) void gemm_bt_kernel(
    const u16* __restrict__ A, const u16* __restrict__ B,
    void* __restrict__ Cv, const void* __restrict__ Rv,
    int M, int N, int K)
{
  constexpr int JN = TN / 32;
  constexpr int NLD = (TN == 128) ? 4 : 3;   // gload_lds per wave per stage
  __shared__ u16 As[3][128 * 32];
  __shared__ u16 Bs[3][TN * 32];
  const int t = threadIdx.x;
  const int lane = t & 63;
  const int wave = t >> 6;
  const int l15 = lane & 15;
  const int quad = lane >> 4;
  const int wm = (wave >> 1) * 64;
  const int wn = (wave & 1) * (TN / 2);
  const int2 bb = xcd_swizzle_xmajor();
  const int m0 = bb.y * 128;
  const int n0 = bb.x * TN;
  const int sw = quad ^ ((l15 >> 1) & 3);

  float4v acc[4][JN] = {};

  const int r0 = t >> 2, q0s = (t & 3) ^ ((t >> 3) & 3);
  const int s1 = 256 + t;
  const int r1 = s1 >> 2, q1s = (s1 & 3) ^ ((s1 >> 3) & 3);

  auto stage = [&](int bi, int kk) {
    gload_lds16(A + (size_t)(m0 + r0) * K + kk + q0s * 8, &As[bi][(wave * 64) * 8]);
    gload_lds16(A + (size_t)(m0 + r1) * K + kk + q1s * 8, &As[bi][(256 + wave * 64) * 8]);
    gload_lds16(B + (size_t)(n0 + r0) * K + kk + q0s * 8, &Bs[bi][(wave * 64) * 8]);
    if (TN == 128)
      gload_lds16(B + (size_t)(n0 + r1) * K + kk + q1s * 8, &Bs[bi][(256 + wave * 64) * 8]);
  };
  auto compute = [&](int bi) {
    short8 af[4], bfr[JN];
#pragma unroll
    for (int i = 0; i < 4; i++)
      af[i] = *(const short8*)(&As[bi][((wm + i * 16 + l15) * 4 + sw) * 8]);
#pragma unroll
    for (int j = 0; j < JN; j++)
      bfr[j] = *(const short8*)(&Bs[bi][((wn + j * 16 + l15) * 4 + sw) * 8]);
#pragma unroll
    for (int i = 0; i < 4; i++)
#pragma unroll
      for (int j = 0; j < JN; j++)
        acc[i][j] = __builtin_amdgcn_mfma_f32_16x16x32_bf16(af[i], bfr[j], acc[i][j], 0, 0, 0);
  };

  const int nk = K >> 5;           // 32-K steps; nk >= 4 at all call sites
  stage(0, 0);
  stage(1, 32);
  int bc = 0, bs = 2;
  for (int i = 0; i + 2 < nk; ++i) {
    stage(bs, (i + 2) << 5);
    WAITV_BAR(2 * NLD);            // stage(i) done; i+1, i+2 stay in flight
    compute(bc);
    BAR_ONLY();                    // all waves done reading buf[bc] before reuse
    bc = (bc == 2) ? 0 : bc + 1;
    bs = (bs == 2) ? 0 : bs + 1;
  }
  WAITV_BAR(NLD);                  // stage(nk-2) done; nk-1 in flight
  compute(bc);
  bc = (bc == 2) ? 0 : bc + 1;
  WAITV_BAR(0);                    // drain last stage
  compute(bc);

#pragma unroll
  for (int i = 0; i < 4; i++) {
#pragma unroll
    for (int r = 0; r < 4; r++) {
      const int row = m0 + wm + i * 16 + quad * 4 + r;
      const size_t base = (size_t)row * N;
#pragma unroll
      for (int j = 0; j < JN; j++) {
        const int col = n0 + wn + j * 16 + l15;
        float v = acc[i][j][r];
        if (RMODE == 1) v += ((const float*)Rv)[base + col];
        if (RMODE == 2) v += bf2f(((const u16*)Rv)[base + col]);
        if (OUTF32) ((float*)Cv)[base + col] = v;
        else        ((u16*)Cv)[base + col] = f2bf(v);
      }
    }
  }
}

// ---------------------------------------------------------------------------
// Fused FFN up-projection — UNCHANGED from r17 (64.6 us measured).
// ---------------------------------------------------------------------------
__global__ __launch_bounds__(512) void gemm_w13_kernel(
    const u16* __restrict__ A, const u16* __restrict__ B1,
    const u16* __restrict__ B2, u16* __restrict__ C,
    int M, int N, int K)
{
  __shared__ u16 As[3][128 * 64];    // 16 KB per buf
  __shared__ u16 B1s[3][128 * 64];
  __shared__ u16 B2s[3][128 * 64];
  const int t = threadIdx.x;
  const int lane = t & 63;
  const int wave = t >> 6;           // 0..7
  const int l15 = lane & 15;
  const int quad = lane >> 4;
  const int wm = (wave >> 2) * 64;   // 2 M-waves
  const int wn = (wave & 3) * 32;    // 4 N-waves
  const int2 bb = xcd_swizzle_xmajor();
  const int m0 = bb.y * 128;
  const int n0 = bb.x * 128;

  float4v accA[4][2] = {};
  float4v accB[4][2] = {};

  const int sub = lane >> 3;         // row within the wave's 8-row group
  const int slot = lane & 7;         // 16B slot within the 128B row

  auto stageA = [&](int bi, int kt) {
#pragma unroll
    for (int j = 0; j < 2; j++) {
      const int r = j * 64 + wave * 8 + sub;
      gload_lds16(A + (size_t)(m0 + r) * K + kt + ((slot ^ (r & 7)) * 8),
                  &As[bi][j * 4096 + wave * 512]);
    }
  };
  auto stageB1 = [&](int bi, int kt) {
#pragma unroll
    for (int j = 0; j < 2; j++) {
      const int r = j * 64 + wave * 8 + sub;
      gload_lds16(B1 + (size_t)(n0 + r) * K + kt + ((slot ^ (r & 7)) * 8),
                  &B1s[bi][j * 4096 + wave * 512]);
    }
  };
  auto stageB2 = [&](int bi, int kt) {
#pragma unroll
    for (int j = 0; j < 2; j++) {
      const int r = j * 64 + wave * 8 + sub;
      gload_lds16(B2 + (size_t)(n0 + r) * K + kt + ((slot ^ (r & 7)) * 8),
                  &B2s[bi][j * 4096 + wave * 512]);
    }
  };

  const int nkt = K >> 6;            // 16 K-tiles
  // prologue: fully stage tiles 0 and 1 (12 loads/wave)
  stageA(0, 0);  stageB1(0, 0);  stageB2(0, 0);
  stageA(1, 64); stageB1(1, 64); stageB2(1, 64);
  WAITV_BAR(6);                      // tile0 landed; tile1 in flight

  int cur = 0;
  for (int i = 0; i < nkt; ++i) {
    const int stg = (cur >= 1) ? cur - 1 : 2;   // (cur+2)%3, tile i+2's buffer
    const int kt2 = (i + 2) << 6;
    // ---------------- phase A ----------------
    short8 af[4][2], b1f[2][2];
#pragma unroll
    for (int ii = 0; ii < 4; ii++) {
      const int R = wm + ii * 16 + l15;
#pragma unroll
      for (int ks = 0; ks < 2; ks++)
        af[ii][ks] = *(const short8*)(&As[cur][R * 64 + (((ks * 4 + quad) ^ (R & 7)) * 8)]);
    }
#pragma unroll
    for (int j = 0; j < 2; j++) {
      const int R = wn + j * 16 + l15;
#pragma unroll
      for (int ks = 0; ks < 2; ks++)
        b1f[j][ks] = *(const short8*)(&B1s[cur][R * 64 + (((ks * 4 + quad) ^ (R & 7)) * 8)]);
    }
    if (i + 2 < nkt) { stageA(stg, kt2); stageB1(stg, kt2); }
    __builtin_amdgcn_s_barrier();
    LGKM0_FENCE();
    __builtin_amdgcn_s_setprio(1);
#pragma unroll
    for (int ii = 0; ii < 4; ii++)
#pragma unroll
      for (int j = 0; j < 2; j++)
#pragma unroll
        for (int ks = 0; ks < 2; ks++)
          accA[ii][j] = __builtin_amdgcn_mfma_f32_16x16x32_bf16(af[ii][ks], b1f[j][ks], accA[ii][j], 0, 0, 0);
    __builtin_amdgcn_s_setprio(0);
    BAR_ONLY();
    // ---------------- phase B ----------------
    short8 b2f[2][2];
#pragma unroll
    for (int j = 0; j < 2; j++) {
      const int R = wn + j * 16 + l15;
#pragma unroll
      for (int ks = 0; ks < 2; ks++)
        b2f[j][ks] = *(const short8*)(&B2s[cur][R * 64 + (((ks * 4 + quad) ^ (R & 7)) * 8)]);
    }
    if (i + 2 < nkt) stageB2(stg, kt2);
    __builtin_amdgcn_s_barrier();
    LGKM0_FENCE();
    __builtin_amdgcn_s_setprio(1);
#pragma unroll
    for (int ii = 0; ii < 4; ii++)
#pragma unroll
      for (int j = 0; j < 2; j++)
#pragma unroll
        for (int ks = 0; ks < 2; ks++)
          accB[ii][j] = __builtin_amdgcn_mfma_f32_16x16x32_bf16(af[ii][ks], b2f[j][ks], accB[ii][j], 0, 0, 0);
    __builtin_amdgcn_s_setprio(0);
    // end-of-tile counted wait: tile i+1 must be landed before next iter reads
    if (i + 2 < nkt)      WAITV_BAR(6);   // tile i+2 (6 loads) stays in flight
    else if (i + 1 < nkt) WAITV_BAR(0);   // drain last staged tile
    cur = (cur == 2) ? 0 : cur + 1;
  }

#pragma unroll
  for (int i = 0; i < 4; i++) {
#pragma unroll
    for (int r = 0; r < 4; r++) {
      const int row = m0 + wm + i * 16 + quad * 4 + r;
      const size_t base = (size_t)row * N;
#pragma unroll
      for (int j = 0; j < 2; j++) {
        const int col = n0 + wn + j * 16 + l15;
        float a = accA[i][j][r];
        float b = accB[i][j][r];
        float h = a / (1.f + __expf(-a)) * b;
        C[base + col] = f2bf(h);
      }
    }
  }
}

// ---------------------------------------------------------------------------
// V transpose — UNCHANGED.
// ---------------------------------------------------------------------------
__global__ __launch_bounds__(256) void vtrans_kernel(
    const u16* __restrict__ qkv, u16* __restrict__ VtG)
{
  __shared__ u16 T[64 * 72];
  const int t = threadIdx.x;
  const int s0 = blockIdx.x * 64;
  const int bh = blockIdx.y, b = bh >> 4, h = bh & 15;
  {
    const int sl = t >> 2, dseg = (t & 3) * 16;
    const size_t src = ((size_t)b * 2048 + s0 + sl) * 3072 + 2048 + h * 64 + dseg;
    int4 v0 = *(const int4*)(qkv + src);
    int4 v1 = *(const int4*)(qkv + src + 8);
    *(int4*)(&T[sl * 72 + dseg]) = v0;
    *(int4*)(&T[sl * 72 + dseg + 8]) = v1;
  }
  __syncthreads();
  {
    const int d = t >> 2, sseg = (t & 3) * 16;
    alignas(16) u16 buf[16];
#pragma unroll
    for (int i = 0; i < 16; i++) buf[i] = T[(sseg + i) * 72 + d];
    u16* dst = VtG + ((size_t)bh * 64 + d) * 2048 + s0 + sseg;
    *(int4*)(dst) = *(const int4*)(&buf[0]);
    *(int4*)(dst + 8) = *(const int4*)(&buf[8]);
  }
}

// ---------------------------------------------------------------------------
// Causal flash attention v3 — r19: 4 q-tiles per block share K/V staging.
// Identity: causal q-tiles 2k and 2k+1 need the SAME chunk range
// (nc = k+1 both). A 512-thread block handles {2k, 2k+1} (waves 0-3 / 4-7)
// plus the mirror pair {30-2k, 31-2k} (nc = 16-k each); 17 chunks total per
// block, uniform. K/V staging traffic and issue HALVE (256 blocks vs 512;
// each staged chunk feeds 8 waves). Grid 8x32 = 256 = exactly 1 block/CU.
// LDS 96 KB. Per-wave inner loop byte-identical to the proven r12 code.
// ---------------------------------------------------------------------------
__global__ __launch_bounds__(512) void attn_kernel(
    const u16* __restrict__ qkv, const u16* __restrict__ VtG,
    u16* __restrict__ outp)
{
  __shared__ u16 Ks[2][2][128 * 32];
  __shared__ u16 Vt[2][4][64 * 32];
  __shared__ u16 Pl[8][2048];
  const int t = threadIdx.x;
  const int lane = t & 63;
  const int wave = t >> 6;        // 0..7
  const int w4 = wave & 3;        // wave within q-tile group
  const int grp = wave >> 2;      // 0: even q-tile, 1: odd q-tile
  const int l15 = lane & 15;
  const int quad = lane >> 4;
  const int sw = quad ^ ((l15 >> 1) & 3);
  // bh-major XCD swizzle: gx=8, nwg=256
  const int lin = blockIdx.x + blockIdx.y * 8;
  const int nl = (lin & 7) * 32 + (lin >> 3);
  const int bh = nl >> 3;
  const int k8 = nl & 7;          // pair index 0..7
  const int b = bh >> 4, h = bh & 15;
  const size_t srow = (size_t)b * 2048;
  const int rr = lane >> 2, qs = (lane & 3) ^ ((lane >> 3) & 3);
  u16* plw = Pl[wave];

  // 32 gload rounds over 8 waves (4 per wave): same layout as r12's stageKV.
  auto stageKV = [&](int bi, int ic) {
    const int c0 = ic * 128;
#pragma unroll
    for (int k = 0; k < 4; k++) {
      const int I = wave * 4 + k;
      if (I < 16) {
        const int half = I >> 3, rb = (I & 7) * 16, row = rb + rr;
        gload_lds16(qkv + (srow + c0 + row) * 3072 + 1024 + h * 64 + half * 32 + qs * 8,
                    &Ks[bi][half][rb * 32]);
      } else {
        const int g = (I - 16) >> 2, rb = ((I - 16) & 3) * 16, row = rb + rr;
        gload_lds16(VtG + ((size_t)bh * 64 + row) * 2048 + c0 + g * 32 + qs * 8,
                    &Vt[bi][g][rb * 32]);
      }
    }
  };

  for (int tsel = 0; tsel < 2; tsel++) {
    const int qt = (tsel ? 30 - 2 * k8 : 2 * k8) + grp;
    const int q = qt * 64 + w4 * 16 + l15;
    const int nc = tsel ? 16 - k8 : k8 + 1;   // block-uniform chunk count

    short8 qf[2];
    {
      const size_t qbase = (srow + q) * 3072 + h * 64;
#pragma unroll
      for (int dh = 0; dh < 2; dh++) {
        int4 raw = *(const int4*)(qkv + qbase + dh * 32 + quad * 8);
        const u16* rp = (const u16*)&raw;
        short8 f;
#pragma unroll
        for (int j = 0; j < 8; j++)
          ((u16*)&f)[j] = f2bf(bf2f(rp[j]) * 0.125f);
        qf[dh] = f;
      }
    }

    float m_i = -INFINITY, l_i = 0.f;
    float4v accO[4] = {};

    stageKV(0, 0);
    for (int ic = 0; ic < nc; ic++) {
      const int cb = ic & 1;
      const int c0 = ic * 128;
      if (ic + 1 < nc) {
        stageKV(cb ^ 1, ic + 1);
        WAITV_BAR(4);              // chunk ic ready; ic+1 stays in flight
      } else {
        WAITV_BAR(0);
      }

      float4v accS[8];
#pragma unroll
      for (int ks = 0; ks < 8; ks++) {
        short8 kf0 = *(const short8*)(&Ks[cb][0][((ks * 16 + l15) * 4 + sw) * 8]);
        short8 kf1 = *(const short8*)(&Ks[cb][1][((ks * 16 + l15) * 4 + sw) * 8]);
        float4v z = {};
        z = __builtin_amdgcn_mfma_f32_16x16x32_bf16(kf0, qf[0], z, 0, 0, 0);
        accS[ks] = __builtin_amdgcn_mfma_f32_16x16x32_bf16(kf1, qf[1], z, 0, 0, 0);
      }

      if (ic == nc - 1) {
#pragma unroll
        for (int ks = 0; ks < 8; ks++)
#pragma unroll
          for (int r = 0; r < 4; r++)
            if (c0 + ks * 16 + quad * 4 + r > q) accS[ks][r] = -INFINITY;
      }

      float cmax = -INFINITY;
#pragma unroll
      for (int ks = 0; ks < 8; ks++)
#pragma unroll
        for (int r = 0; r < 4; r++) cmax = fmaxf(cmax, accS[ks][r]);
      cmax = fmaxf(cmax, __shfl_xor(cmax, 16));
      cmax = fmaxf(cmax, __shfl_xor(cmax, 32));
      const float mn = fmaxf(m_i, cmax);
      const float alpha = __expf(m_i - mn);

      float psum = 0.f;
#pragma unroll
      for (int ks = 0; ks < 8; ks++) {
        float p0 = __expf(accS[ks][0] - mn);
        float p1 = __expf(accS[ks][1] - mn);
        float p2 = __expf(accS[ks][2] - mn);
        float p3 = __expf(accS[ks][3] - mn);
        psum += (p0 + p1) + (p2 + p3);
        u16x4 pk;
        pk.x = f2bf(p0); pk.y = f2bf(p1); pk.z = f2bf(p2); pk.w = f2bf(p3);
        const int seg = ((ks & 1) * 2 + (quad >> 1)) ^ ((l15 >> 1) & 3);
        *(u16x4*)(&plw[(ks >> 1) * 512 + (l15 * 4 + seg) * 8 + (quad & 1) * 4]) = pk;
      }
      psum += __shfl_xor(psum, 16);
      psum += __shfl_xor(psum, 32);
      l_i = l_i * alpha + psum;
      m_i = mn;
#pragma unroll
      for (int ds = 0; ds < 4; ds++)
#pragma unroll
        for (int r = 0; r < 4; r++) accO[ds][r] *= alpha;

      __threadfence_block();

#pragma unroll
      for (int kh = 0; kh < 4; kh++) {
        short8 pf = *(const short8*)(&plw[kh * 512 + (l15 * 4 + sw) * 8]);
#pragma unroll
        for (int ds = 0; ds < 4; ds++) {
          short8 vf = *(const short8*)(&Vt[cb][kh][((ds * 16 + l15) * 4 + sw) * 8]);
          accO[ds] = __builtin_amdgcn_mfma_f32_16x16x32_bf16(vf, pf, accO[ds], 0, 0, 0);
        }
      }
      BAR_ONLY();                  // buffer cb safe to restage next iteration
    }

    const float invl = 1.f / l_i;
    const size_t obase = (srow + q) * 1024 + h * 64;
#pragma unroll
    for (int ds = 0; ds < 4; ds++) {
      u16x4 pk;
      pk.x = f2bf(accO[ds][0] * invl);
      pk.y = f2bf(accO[ds][1] * invl);
      pk.z = f2bf(accO[ds][2] * invl);
      pk.w = f2bf(accO[ds][3] * invl);
      *(u16x4*)(outp + obase + ds * 16 + quad * 4) = pk;
    }
  }
}

// ---------------------------------------------------------------------------
// RMSNorm — UNCHANGED.
// ---------------------------------------------------------------------------
template <bool XF32>
__global__ __launch_bounds__(256) void rmsnorm_kernel(
    const void* __restrict__ xv, const float* __restrict__ g, u16* __restrict__ o)
{
  const int row = blockIdx.x;
  const int t = threadIdx.x;
  float f0, f1, f2, f3;
  if (XF32) {
    float4 v = *(const float4*)((const float*)xv + (size_t)row * 1024 + t * 4);
    f0 = v.x; f1 = v.y; f2 = v.z; f3 = v.w;
  } else {
    int2 v = *(const int2*)((const u16*)xv + (size_t)row * 1024 + t * 4);
    const u16* p = (const u16*)&v;
    f0 = bf2f(p[0]); f1 = bf2f(p[1]); f2 = bf2f(p[2]); f3 = bf2f(p[3]);
  }
  float ss = f0 * f0 + f1 * f1 + f2 * f2 + f3 * f3;
#pragma unroll
  for (int off = 32; off > 0; off >>= 1) ss += __shfl_down(ss, off);
  __shared__ float red[4];
  if ((t & 63) == 0) red[t >> 6] = ss;
  __syncthreads();
  const float tot = red[0] + red[1] + red[2] + red[3];
  const float inv = rsqrtf(tot * (1.0f / 1024.0f) + 1e-5f);
  float4 gv = *(const float4*)(g + t * 4);
  u16x4 ov;
  ov.x = f2bf(f0 * gv.x * inv);
  ov.y = f2bf(f1 * gv.y * inv);
  ov.z = f2bf(f2 * gv.z * inv);
  ov.w = f2bf(f3 * gv.w * inv);
  *(u16x4*)(o + (size_t)row * 1024 + t * 4) = ov;
}

// ---------------------------------------------------------------------------
// Inputs (fp32): x wqkv wo g1 g2 w1 w2 w3. OUTPUT fp32.
// ws (72 MB): bf16 weights 24 + S1 8 + S2 24 + S3 8 + VtG 8.
// ---------------------------------------------------------------------------
extern "C" void kernel_launch(void* const* d_in, const int* in_sizes, int n_in,
                              void* d_out, int out_size, void* d_ws, size_t ws_size,
                              hipStream_t stream)
{
  const float* x    = (const float*)d_in[0];
  const float* wqkv = (const float*)d_in[1];
  const float* wo   = (const float*)d_in[2];
  const float* g1   = (const float*)d_in[3];
  const float* g2   = (const float*)d_in[4];
  const float* w1   = (const float*)d_in[5];
  const float* w2   = (const float*)d_in[6];
  const float* w3   = (const float*)d_in[7];
  float* out = (float*)d_out;
  char* ws = (char*)d_ws;
  (void)in_sizes; (void)n_in; (void)out_size; (void)ws_size;

  size_t off = 0;
  auto alloc = [&](size_t bytes) { void* p = ws + off; off += (bytes + 255) & ~(size_t)255; return p; };
  u16* wqkvb = (u16*)alloc((size_t)3072 * 1024 * 2);
  u16* wob   = (u16*)alloc((size_t)1024 * 1024 * 2);
  u16* w1b   = (u16*)alloc((size_t)2688 * 1024 * 2);
  u16* w2b   = (u16*)alloc((size_t)2688 * 1024 * 2);
  u16* w3b   = (u16*)alloc((size_t)2688 * 1024 * 2);
  u16* S1    = (u16*)alloc((size_t)4096 * 1024 * 2);
  u16* S2    = (u16*)alloc((size_t)4096 * 3072 * 2);
  u16* S3    = (u16*)alloc((size_t)4096 * 1024 * 2);
  u16* VtG   = (u16*)alloc((size_t)32 * 64 * 2048 * 2);

  PrepArgs pa;
  const float* srcs[5] = {wqkv, wo, w1, w2, w3};
  u16* dsts[5] = {wqkvb, wob, w1b, w2b, w3b};
  const int nelem[5] = {3072 * 1024, 1024 * 1024, 2688 * 1024, 2688 * 1024, 2688 * 1024};
  int pre = 0;
  for (int i = 0; i < 5; i++) {
    pa.src[i] = srcs[i];
    pa.dst[i] = dsts[i];
    pa.pre[i] = pre;
    pre += nelem[i] / 8;
  }
  pa.pre[5] = pre;
  prep_kernel<<<(pre + 255) / 256, 256, 0, stream>>>(pa);

  rmsnorm_kernel<true><<<4096, 256, 0, stream>>>(x, g1, S1);                        // xn
  gemm_bt_kernel<0, false, 128><<<dim3(24, 32), 256, 0, stream>>>(S1, wqkvb, S2,
                                                  nullptr, 4096, 3072, 1024);       // qkv
  vtrans_kernel<<<dim3(32, 32), 256, 0, stream>>>(S2, VtG);                         // V^T
  attn_kernel<<<dim3(8, 32), 512, 0, stream>>>(S2, VtG, S1);                        // att
  gemm_bt_kernel<1, false, 64><<<dim3(16, 32), 256, 0, stream>>>(S1, wob, S3, x,
                                                  4096, 1024, 1024);                // x1
  rmsnorm_kernel<false><<<4096, 256, 0, stream>>>(S3, g2, S1);                      // xn2
  gemm_w13_kernel<<<dim3(21, 32), 512, 0, stream>>>(S1, w1b, w3b, S2,
                                                  4096, 2688, 1024);                // h
  gemm_bt_kernel<2, true, 64><<<dim3(16, 32), 256, 0, stream>>>(S2, w2b, out, S3,
                                                  4096, 1024, 2688);                // out fp32
}